// Round 1
// baseline (106.324 us; speedup 1.0000x reference)
//
#include <hip/hip_runtime.h>
#include <math.h>

// LengthRegulator: B=16, T=512, D=512, T_OUT=2560, all float32. Fully fused:
// ONE kernel, grid (T_OUT/32, B) x 512 threads (8 waves). Each block:
//   1. coalesced 2 KB dur load (L2-hot),
//   2. hybrid scan (wave shfl_up; each thread sums <=7 preceding wave totals
//      from LDS broadcast reads) -> ends[] in LDS, TWO barriers total
//      (down from 3: removed the 8-thread combine step + its barrier),
//   3. per-wave search: wave w owns frames 4w..4w+3; lanes 0-3 each run one
//      dependent binary-search chain in parallel (same latency as 2 frames,
//      2x the amortization); NO barrier after -- waves retire independently,
//   4. per-wave copy: 4 frames x 2 float4/lane, pipelined 2 frames at a time
//      to keep live regs ~= old kernel (<64 VGPR, 8 waves/SIMD). Output uses
//      nontemporal stores (84 MB pure stream; don't churn L2 / evict x rows).
// 32 frames/block halves block count 2560->1280: total scan+search preamble
// (the only overhead above the ~16.5 us BW floor of 84 MB write + ~18 MB
// fetch) is halved. Zeros past total length. dur_us also carries ~75-80 us
// of harness re-poison/restore traffic (335 MB fill at ~79% HBM peak visible
// in rocprof every iteration) -- that part is not addressable from here.

#define LR_B 16
#define LR_T 512
#define LR_D 512
#define LR_TOUT 2560
#define FRAMES_PER_BLOCK 32   // 8 waves x 4 frames/wave

typedef float f32x4 __attribute__((ext_vector_type(4)));

__global__ __launch_bounds__(512) void lr_fused_kernel(
        const float* __restrict__ x,
        const float* __restrict__ dur,
        float* __restrict__ out) {
    const int b    = blockIdx.y;
    const int base = blockIdx.x * FRAMES_PER_BLOCK;
    const int tid  = threadIdx.x;          // 512 threads
    const int lane = tid & 63;
    const int w    = tid >> 6;             // wave id 0..7

    __shared__ int s[LR_T];                // inclusive cumsum (ends)
    __shared__ int wsum[8];                // per-wave totals

    // --- scan: wave-level shfl_up inclusive scan, then cross-wave combine ---
    int v = (int)floorf(dur[b * LR_T + tid] + 0.5f);
    #pragma unroll
    for (int off = 1; off < 64; off <<= 1) {
        int n = __shfl_up(v, off, 64);
        if (lane >= off) v += n;
    }
    if (lane == 63) wsum[w] = v;
    __syncthreads();
    // Each thread sums the totals of preceding waves (uniform-address LDS
    // reads -> broadcast, no conflict). Replaces 8-thread shfl scan + barrier.
    int prefix = 0;
    #pragma unroll
    for (int i = 0; i < 7; ++i)
        prefix += (i < w) ? wsum[i] : 0;
    s[tid] = v + prefix;
    __syncthreads();

    const int total = s[LR_T - 1];

    // --- per-wave search: wave w owns frames 4w..4w+3 ---
    // Lanes 0..3 each run one dependent binary-search chain; broadcast below.
    int r = -1;
    if (lane < 4) {
        const int j = base + 4 * w + lane;
        if (j < total) {
            int lo = 0, hi = LR_T;         // first idx with s[idx] > j
            while (lo < hi) {
                const int mid = (lo + hi) >> 1;
                if (s[mid] > j) hi = mid; else lo = mid + 1;
            }
            r = (lo < LR_T - 1) ? lo : (LR_T - 1);
        }
    }

    // --- per-wave copy: 4 frames, pipelined 2 at a time (reg pressure) ---
    const size_t xb    = (size_t)b * LR_T * LR_D;
    const size_t obase = (size_t)(b * LR_TOUT + base + 4 * w) * LR_D;

    #pragma unroll
    for (int p = 0; p < 2; ++p) {
        const int sA = __shfl(r, 2 * p,     64);
        const int sB = __shfl(r, 2 * p + 1, 64);

        f32x4 a0 = {0.f, 0.f, 0.f, 0.f}, a1 = a0, c0 = a0, c1 = a0;
        if (sA >= 0) {
            const f32x4* row = (const f32x4*)(x + xb + (size_t)sA * LR_D);
            a0 = row[lane];
            a1 = row[lane + 64];
        }
        if (sB >= 0) {
            const f32x4* row = (const f32x4*)(x + xb + (size_t)sB * LR_D);
            c0 = row[lane];
            c1 = row[lane + 64];
        }
        f32x4* oA = (f32x4*)(out + obase + (size_t)(2 * p)     * LR_D);
        f32x4* oB = (f32x4*)(out + obase + (size_t)(2 * p + 1) * LR_D);
        __builtin_nontemporal_store(a0, oA + lane);
        __builtin_nontemporal_store(a1, oA + lane + 64);
        __builtin_nontemporal_store(c0, oB + lane);
        __builtin_nontemporal_store(c1, oB + lane + 64);
    }
}

extern "C" void kernel_launch(void* const* d_in, const int* in_sizes, int n_in,
                              void* d_out, int out_size, void* d_ws, size_t ws_size,
                              hipStream_t stream) {
    const float* x   = (const float*)d_in[0];   // [B, T, D] f32
    const float* dur = (const float*)d_in[1];   // [B, T]    f32
    float* out = (float*)d_out;                 // [B, T_OUT, D] f32

    dim3 grid(LR_TOUT / FRAMES_PER_BLOCK, LR_B);   // (80, 16)
    lr_fused_kernel<<<grid, 512, 0, stream>>>(x, dur, out);
}

// Round 2
// 102.270 us; speedup vs baseline: 1.0396x; 1.0396x over previous
//
#include <hip/hip_runtime.h>
#include <math.h>

// LengthRegulator: B=16, T=512, D=512, T_OUT=2560, all float32. Fully fused:
// ONE kernel, grid (T_OUT/32, B) x 512 threads (8 waves). Each block:
//   1. coalesced 2 KB dur load (L2-hot),
//   2. hybrid scan (wave shfl_up; each thread sums <=7 preceding wave totals
//      from LDS broadcast reads) -> ends[] in LDS, TWO barriers total,
//   3. per-wave search: wave w owns frames 4w..4w+3; lanes 0-3 each run one
//      dependent binary-search chain in parallel; NO barrier after -- waves
//      retire independently,
//   4. per-wave copy: 4 frames x 2 float4/lane, pipelined 2 frames at a time
//      to keep live regs < 64 VGPR (8 waves/SIMD). PLAIN stores: R1's
//      __builtin_nontemporal_store regressed +4.5 us -- nt bypasses L2
//      write-combining and drops effective write BW on the 84 MB stream
//      (fill kernel with regular stores sustains 6.36 TB/s; nt landed well
//      below). Reverted; structure changes kept.
// 32 frames/block halves block count 2560->1280: total scan+search preamble
// (the only overhead above the ~16.5 us BW floor of 84 MB write + ~18 MB
// fetch) is halved. Zeros past total length. dur_us also carries ~75-80 us
// of harness re-poison/restore traffic (335 MB fill at ~79% HBM peak visible
// in rocprof every iteration) -- not addressable from here.

#define LR_B 16
#define LR_T 512
#define LR_D 512
#define LR_TOUT 2560
#define FRAMES_PER_BLOCK 32   // 8 waves x 4 frames/wave

typedef float f32x4 __attribute__((ext_vector_type(4)));

__global__ __launch_bounds__(512) void lr_fused_kernel(
        const float* __restrict__ x,
        const float* __restrict__ dur,
        float* __restrict__ out) {
    const int b    = blockIdx.y;
    const int base = blockIdx.x * FRAMES_PER_BLOCK;
    const int tid  = threadIdx.x;          // 512 threads
    const int lane = tid & 63;
    const int w    = tid >> 6;             // wave id 0..7

    __shared__ int s[LR_T];                // inclusive cumsum (ends)
    __shared__ int wsum[8];                // per-wave totals

    // --- scan: wave-level shfl_up inclusive scan, then cross-wave combine ---
    int v = (int)floorf(dur[b * LR_T + tid] + 0.5f);
    #pragma unroll
    for (int off = 1; off < 64; off <<= 1) {
        int n = __shfl_up(v, off, 64);
        if (lane >= off) v += n;
    }
    if (lane == 63) wsum[w] = v;
    __syncthreads();
    // Each thread sums the totals of preceding waves (uniform-address LDS
    // reads -> broadcast, no conflict). Replaces 8-thread shfl scan + barrier.
    int prefix = 0;
    #pragma unroll
    for (int i = 0; i < 7; ++i)
        prefix += (i < w) ? wsum[i] : 0;
    s[tid] = v + prefix;
    __syncthreads();

    const int total = s[LR_T - 1];

    // --- per-wave search: wave w owns frames 4w..4w+3 ---
    // Lanes 0..3 each run one dependent binary-search chain; broadcast below.
    int r = -1;
    if (lane < 4) {
        const int j = base + 4 * w + lane;
        if (j < total) {
            int lo = 0, hi = LR_T;         // first idx with s[idx] > j
            while (lo < hi) {
                const int mid = (lo + hi) >> 1;
                if (s[mid] > j) hi = mid; else lo = mid + 1;
            }
            r = (lo < LR_T - 1) ? lo : (LR_T - 1);
        }
    }

    // --- per-wave copy: 4 frames, pipelined 2 at a time (reg pressure) ---
    const size_t xb    = (size_t)b * LR_T * LR_D;
    const size_t obase = (size_t)(b * LR_TOUT + base + 4 * w) * LR_D;

    #pragma unroll
    for (int p = 0; p < 2; ++p) {
        const int sA = __shfl(r, 2 * p,     64);
        const int sB = __shfl(r, 2 * p + 1, 64);

        f32x4 a0 = {0.f, 0.f, 0.f, 0.f}, a1 = a0, c0 = a0, c1 = a0;
        if (sA >= 0) {
            const f32x4* row = (const f32x4*)(x + xb + (size_t)sA * LR_D);
            a0 = row[lane];
            a1 = row[lane + 64];
        }
        if (sB >= 0) {
            const f32x4* row = (const f32x4*)(x + xb + (size_t)sB * LR_D);
            c0 = row[lane];
            c1 = row[lane + 64];
        }
        f32x4* oA = (f32x4*)(out + obase + (size_t)(2 * p)     * LR_D);
        f32x4* oB = (f32x4*)(out + obase + (size_t)(2 * p + 1) * LR_D);
        oA[lane]      = a0;
        oA[lane + 64] = a1;
        oB[lane]      = c0;
        oB[lane + 64] = c1;
    }
}

extern "C" void kernel_launch(void* const* d_in, const int* in_sizes, int n_in,
                              void* d_out, int out_size, void* d_ws, size_t ws_size,
                              hipStream_t stream) {
    const float* x   = (const float*)d_in[0];   // [B, T, D] f32
    const float* dur = (const float*)d_in[1];   // [B, T]    f32
    float* out = (float*)d_out;                 // [B, T_OUT, D] f32

    dim3 grid(LR_TOUT / FRAMES_PER_BLOCK, LR_B);   // (80, 16)
    lr_fused_kernel<<<grid, 512, 0, stream>>>(x, dur, out);
}